// Round 3
// baseline (134.635 us; speedup 1.0000x reference)
//
#include <hip/hip_runtime.h>
#include <hip/hip_bf16.h>

// LSTM_71382356459716 R11: two independent batch groups per block (T15-style).
// R10 post-mortem: 8 waves/SIMD (occ 30->55%) was FLAT (59.5us) -> wave-count
// latency hiding is dead: all waves lockstep on the same barrier; the per-step
// serial chain (ds_read h ~120cy -> 3-dep MFMA -> ~220cy trans/VALU act chain
// -> write -> barrier) re-exposes every step. VALUBusy 52% = activations;
// remaining 48% = convoy latency.
// R11: each block owns TWO independent 16-row groups (ROWS 32, 512 blocks,
// 2/CU). A-frags (weights) shared -> no extra W VGPR. Per barrier phase each
// wave runs two independent MFMA->activation chains; compiler interleaves
// statically, so group B's issue fills group A's dependency stalls INSIDE the
// wave. Barriers per group-step halved. Activation math, prep, per-group LDS
// layout identical to R10 (passed, absmax 0.00195).
// Prediction: 59 -> 36-44us, VALUBusy -> 70-80%, MfmaUtil -> ~22%.

namespace {
constexpr int B_TOT   = 16384;
constexpr int T_STEPS = 28;
constexpr int IN_DIM  = 28;
constexpr int HID     = 64;
constexpr int OUT_DIM = 10;
constexpr int ROWS    = 16;    // batch rows per group
constexpr int GROUPS  = 2;     // independent groups per block
constexpr int THREADS = 512;   // 8 waves
constexpr int KP      = 104;   // row stride in shorts (208 B, odd*16B)
constexpr int XROW    = T_STEPS * IN_DIM;  // 784 floats per batch row
constexpr int NFRAG   = 16 * 3;            // 16 Mtiles * 3 kchunks
constexpr int WS_ELEMS = NFRAG * 64 * 8;   // 24576 bf16 = 48 KB
}

typedef __attribute__((ext_vector_type(8))) short short8v;   // 8 bf16
typedef __attribute__((ext_vector_type(4))) short short4v;
typedef __attribute__((ext_vector_type(4))) float float4v;

__device__ __forceinline__ short f2bf_cold(float f) {
  union { float f; unsigned u; } v; v.f = f;
  unsigned r = v.u + 0x7FFFu + ((v.u >> 16) & 1u);
  return (short)(r >> 16);
}
__device__ __forceinline__ float bf2f(short s) {
  union { unsigned u; float f; } v; v.u = ((unsigned)(unsigned short)s) << 16;
  return v.f;
}
__device__ __forceinline__ unsigned pk2(float a, float b) {  // 2xf32->bf16x2
  __hip_bfloat162 h = __float22bfloat162_rn(float2{a, b});
  union { __hip_bfloat162 h; unsigned u; } cv; cv.h = h; return cv.u;
}

// ---- setup: permute weights+bias into MFMA A-frag order (runs every call) --
// ws layout: frag f = mt*3 + kc, lane l, elem j:
//   ws[(f*64 + l)*8 + j] = bf16 of A[m=16*mt+(l&15)][k=kc*32+(l>>4)*8+j]
// gate row g = (m&3)*64 + (m>>2); k<28 -> W_ih, k==28 -> b_ih+b_hh,
// 29..31 -> 0, k>=32 -> W_hh[:, u(k-32)] where stored col c holds unit
// u(c) = 8*(c>>3) + 4*(c&1) + ((c>>1)&3)  (h-store permutation).
// All values pre-scaled by -log2(e) (gates i,f,o) / -2*log2(e) (gate g) so
// the main kernel uses bare exp2.
__global__ void lstm_prep(const float* __restrict__ W_ih,
                          const float* __restrict__ W_hh,
                          const float* __restrict__ b_ih,
                          const float* __restrict__ b_hh,
                          unsigned short* __restrict__ ws) {
  int idx = blockIdx.x * blockDim.x + threadIdx.x;
  if (idx >= WS_ELEMS) return;
  int j  = idx & 7;
  int l  = (idx >> 3) & 63;
  int fk = idx >> 9;            // mt*3 + kc
  int kc = fk % 3;
  int mt = fk / 3;
  int m  = 16 * mt + (l & 15);
  int unit = m >> 2, type = m & 3;
  int g  = type * 64 + unit;
  int k  = kc * 32 + (l >> 4) * 8 + j;
  float v = 0.0f;
  if (k < IN_DIM)        v = W_ih[g * IN_DIM + k];
  else if (k == IN_DIM)  v = b_ih[g] + b_hh[g];
  else if (k >= 32) {
    int c = k - 32;
    int u = 8 * (c >> 3) + 4 * (c & 1) + ((c >> 1) & 3);
    v = W_hh[g * HID + u];
  }
  // fold exp argument scaling into the weights (type 2 == gate g -> tanh)
  v *= (type == 2) ? -2.8853900817779268f : -1.4426950408889634f;
  ws[idx] = (unsigned short)f2bf_cold(v);
}

__global__ __attribute__((amdgpu_flat_work_group_size(THREADS, THREADS),
                          amdgpu_waves_per_eu(4, 4)))
void lstm_mfma8(const float* __restrict__ x,
                const unsigned short* __restrict__ wfrag,
                const float* __restrict__ W_fc,
                const float* __restrict__ b_fc, float* __restrict__ out) {
  // [group][buf][row][k]: cols 0..27 x, 28 = 1.0 (bias), 32..95 h (permuted)
  __shared__ short hs[GROUPS][2][ROWS][KP];

  const int tid  = threadIdx.x;
  const int lane = tid & 63;
  const int w    = tid >> 6;      // wave 0..7 -> units 8w..8w+7
  const int l15  = lane & 15;
  const int q    = lane >> 4;     // 0..3
  const int b0   = blockIdx.x * (ROWS * GROUPS);

  // ---- stationary A: 6 coalesced 16B loads per lane (frag-order from ws) --
  short8v a[2][3];
#pragma unroll
  for (int i = 0; i < 2; ++i)
#pragma unroll
    for (int kc = 0; kc < 3; ++kc)
      a[i][kc] = *(const short8v*)&wfrag[((((2 * w + i) * 3) + kc) * 64 + lane) * 8];

  // zero all buffers, then set the constant bias column (never overwritten)
  for (int idx = tid; idx < GROUPS * 2 * ROWS * KP; idx += THREADS)
    (&hs[0][0][0][0])[idx] = 0;
  __syncthreads();
  if (tid < GROUPS * 2 * ROWS)   // g = tid>>5, buf = (tid>>4)&1, row = tid&15
    hs[tid >> 5][(tid >> 4) & 1][tid & 15][IN_DIM] = (short)0x3F80;  // bf16 1.0

  // ---- x staging: lanes 0..13 stage group 0, lanes 14..27 group 1 ---------
  const bool stager = (lane < 28);
  const int  sg = (lane >= 14) ? 1 : 0;
  const int  s  = w * 14 + (lane - 14 * sg);   // 0..111 per group
  const int  sr = s / 7;
  const int  sc = s - 7 * sr;
  const float* xptr = x + (size_t)(b0 + sg * ROWS + sr) * XROW + sc * 4;

  // stage x_0 directly; preload x_1 into the in-flight register
  float4 xfly = {0.f, 0.f, 0.f, 0.f};
  if (stager) {
    float4 x0 = *(const float4*)xptr;
    short4v sv;
    unsigned plo = pk2(x0.x, x0.y), phi = pk2(x0.z, x0.w);
    sv[0] = (short)(plo & 0xFFFF); sv[1] = (short)(plo >> 16);
    sv[2] = (short)(phi & 0xFFFF); sv[3] = (short)(phi >> 16);
    *(short4v*)&hs[sg][0][sr][sc * 4] = sv;
    xfly = *(const float4*)(xptr + 1 * IN_DIM);   // x_1, consumed at t=0
  }
  __syncthreads();

  float c_state[GROUPS][2] = {{0.f, 0.f}, {0.f, 0.f}};

  for (int t = 0; t < T_STEPS; ++t) {
    const int cur = t & 1, nxt = cur ^ 1;

    // B-frags for both groups: lane holds B[k = kc*32 + q*8 + j][n = l15]
    short8v bf[GROUPS][3];
#pragma unroll
    for (int gg = 0; gg < GROUPS; ++gg) {
      bf[gg][0] = *(const short8v*)&hs[gg][cur][l15][q * 8];
      bf[gg][1] = *(const short8v*)&hs[gg][cur][l15][32 + q * 8];
      bf[gg][2] = *(const short8v*)&hs[gg][cur][l15][64 + q * 8];
    }

    // store x_{t+1} (loaded a full step ago), issue load of x_{t+2}
    if (stager) {
      if (t + 1 < T_STEPS) {
        short4v sv;
        unsigned plo = pk2(xfly.x, xfly.y), phi = pk2(xfly.z, xfly.w);
        sv[0] = (short)(plo & 0xFFFF); sv[1] = (short)(plo >> 16);
        sv[2] = (short)(phi & 0xFFFF); sv[3] = (short)(phi >> 16);
        *(short4v*)&hs[sg][nxt][sr][sc * 4] = sv;
      }
      if (t + 2 < T_STEPS)
        xfly = *(const float4*)(xptr + (t + 2) * IN_DIM);
    }

    const float4v zero4 = {0.f, 0.f, 0.f, 0.f};
    float4v acc[GROUPS][2];
#pragma unroll
    for (int gg = 0; gg < GROUPS; ++gg) {
#pragma unroll
      for (int i = 0; i < 2; ++i)
        acc[gg][i] = __builtin_amdgcn_mfma_f32_16x16x32_bf16(a[i][0], bf[gg][0], zero4, 0, 0, 0);
#pragma unroll
      for (int i = 0; i < 2; ++i)
        acc[gg][i] = __builtin_amdgcn_mfma_f32_16x16x32_bf16(a[i][1], bf[gg][1], acc[gg][i], 0, 0, 0);
#pragma unroll
      for (int i = 0; i < 2; ++i)
        acc[gg][i] = __builtin_amdgcn_mfma_f32_16x16x32_bf16(a[i][2], bf[gg][2], acc[gg][i], 0, 0, 0);
    }

    // activations; exp-scales pre-folded into A so these are bare exp2.
    // Two independent chains (gg=0,1) -> compiler interleaves to hide latency.
#pragma unroll
    for (int gg = 0; gg < GROUPS; ++gg) {
      float hv[2];
#pragma unroll
      for (int i = 0; i < 2; ++i) {
        float4v g4 = acc[gg][i];
        float Ei = __builtin_amdgcn_exp2f(g4[0]);
        float Ef = __builtin_amdgcn_exp2f(g4[1]);
        float Eg = __builtin_amdgcn_exp2f(g4[2]);
        float Eo = __builtin_amdgcn_exp2f(g4[3]);
        float di = 1.0f + Ei, df = 1.0f + Ef;
        float r1 = __builtin_amdgcn_rcpf(di * df);
        float iv = r1 * df;
        float fv = r1 * di;
        float gv = fmaf(2.0f, __builtin_amdgcn_rcpf(1.0f + Eg), -1.0f);
        float cn = fmaf(fv, c_state[gg][i], iv * gv);
        c_state[gg][i] = cn;
        float ct = fminf(fmaxf(cn, -15.0f), 15.0f);   // tanh saturated beyond
        float Ec = __builtin_amdgcn_exp2f(-2.8853900817779268f * ct);
        float dn = 1.0f + Eo, dc = 1.0f + Ec;
        float r2 = __builtin_amdgcn_rcpf(dn * dc);
        float ov = r2 * dc;
        float tc = fmaf(2.0f * r2, dn, -1.0f);
        hv[i] = ov * tc;
      }
      // packed bf16; unit 8w+4i+q lands at col 8w+2q+i -> single b32 store
      unsigned p01 = pk2(hv[0], hv[1]);
      *(unsigned*)&hs[gg][nxt][l15][32 + 8 * w + 2 * q] = p01;
    }

    __syncthreads();
  }

  // ---- FC epilogue: final h in buf 0 (t=27 wrote nxt = 0), cols 32..95 ----
  // stored col c holds unit u(c) = 8*(c>>3) + 4*(c&1) + ((c>>1)&3)
  if (tid < GROUPS * ROWS * OUT_DIM) {   // 320 outputs
    const int r = tid / OUT_DIM;         // 0..31
    const int o = tid - r * OUT_DIM;
    const int gg = r >> 4, rr = r & 15;
    float sacc = b_fc[o];
#pragma unroll
    for (int c = 0; c < HID; ++c) {
      int u = 8 * (c >> 3) + 4 * (c & 1) + ((c >> 1) & 3);
      sacc += bf2f(hs[gg][0][rr][32 + c]) * W_fc[o * HID + u];
    }
    out[(b0 + gg * ROWS + rr) * OUT_DIM + o] = sacc;
  }
}

extern "C" void kernel_launch(void* const* d_in, const int* in_sizes, int n_in,
                              void* d_out, int out_size, void* d_ws, size_t ws_size,
                              hipStream_t stream) {
  const float* x    = (const float*)d_in[0];
  const float* W_ih = (const float*)d_in[1];
  const float* W_hh = (const float*)d_in[2];
  const float* b_ih = (const float*)d_in[3];
  const float* b_hh = (const float*)d_in[4];
  const float* W_fc = (const float*)d_in[5];
  const float* b_fc = (const float*)d_in[6];
  float* out = (float*)d_out;
  unsigned short* ws = (unsigned short*)d_ws;   // 48 KB frag-ordered weights

  lstm_prep<<<(WS_ELEMS + 255) / 256, 256, 0, stream>>>(W_ih, W_hh, b_ih, b_hh, ws);

  dim3 grid(B_TOT / (ROWS * GROUPS));   // 512 blocks -> 2 blocks/CU
  dim3 block(THREADS);
  lstm_mfma8<<<grid, block, 0, stream>>>(x, ws, W_fc, b_fc, out);
}